// Round 3
// baseline (7412.366 us; speedup 1.0000x reference)
//
#include <hip/hip_runtime.h>
#include <cmath>

#define CLIPV 20.0f
#define EPSV 1e-6f

__device__ __forceinline__ float sigmoidf_(float x){ return 1.0f/(1.0f + expf(-x)); }
__device__ __forceinline__ float softplusf_(float x){ return (x > 20.0f) ? x : log1pf(expf(x)); }
__device__ __forceinline__ float clipf_(float x){ return fminf(fmaxf(x, -CLIPV), CLIPV); }

__device__ __forceinline__ float wave_sum64(float v){
  #pragma unroll
  for (int off=32; off>=1; off>>=1) v += __shfl_xor(v, off, 64);
  return v;
}
__device__ __forceinline__ float wave_max64(float v){
  #pragma unroll
  for (int off=32; off>=1; off>>=1) v = fmaxf(v, __shfl_xor(v, off, 64));
  return v;
}
__device__ __forceinline__ float block_sum256(float v, float* s_red){
  v = wave_sum64(v);
  __syncthreads();
  if ((threadIdx.x & 63) == 0) s_red[threadIdx.x>>6] = v;
  __syncthreads();
  return s_red[0]+s_red[1]+s_red[2]+s_red[3];
}
__device__ __forceinline__ float block_max256(float v, float* s_red){
  v = wave_max64(v);
  __syncthreads();
  if ((threadIdx.x & 63) == 0) s_red[threadIdx.x>>6] = v;
  __syncthreads();
  return fmaxf(fmaxf(s_red[0],s_red[1]), fmaxf(s_red[2],s_red[3]));
}

// ---- workspace layout (float offsets) ----
#define WS_MEM    0
#define WS_LINK   1048576
#define WS_PREC   5242880   /* 2 x 16384 */
#define WS_WR     5275648
#define WS_WW     5341184
#define WS_USAGE  5357568
#define WS_RVECT  5373952   /* transposed [256][64] */
#define WS_HT     5390336   /* 2 x [512][64] */
#define WS_HCT    5455872   /* 2 x [512][64] */
#define WS_XI     5521408   /* [64][471] */
#define WS_QSUM   5551552   /* [64][1024] */
#define WS_BAR    5617088   /* 1024 ints: subs[16*32], root, gen */
#define WS_ZONEA  5618112   /* memset extent */
#define WS_QV     5618112   /* [1280][300] */
#define WS_HID1   5618112   /* overlay: QV dead by fc1 time */
#define WS_ZONEC  6002112   /* 2,621,440 floats: gxp / cxp / gemm partials */
#define WS_IMGF   8623552
#define WS_COMB   8689088
#define WS_LASTB  8754624   /* [64][1280] */

// ------------------------- embedding -------------------------
__global__ void embed_kernel(const int* __restrict__ qst, const float* __restrict__ emb,
                             float* __restrict__ qv){
  int idx = blockIdx.x*256 + threadIdx.x;
  if (idx >= 1280*300) return;
  int m = idx / 300;
  int e = idx - m*300;
  int t = m >> 6, b = m & 63;
  int tok = qst[b*20 + t];
  qv[idx] = tanhf(emb[(size_t)tok*300 + e]);
}

// ------------------------- generic tiled f32 GEMM (float4 loads) ------------------
__global__ __launch_bounds__(256) void gemm64(
    int M, int N, int Ktot, int KS,
    const float* __restrict__ A, int lda,
    const float* __restrict__ B,
    const float* __restrict__ bias,
    float* __restrict__ out, float* __restrict__ part, int mode)
{
  __shared__ float As[32*68];
  __shared__ float Bs[32*68];
  int tid = threadIdx.x;
  int nb = blockIdx.x*64, ks = blockIdx.y, mb = blockIdx.z*64;
  int Kc = (((Ktot + KS - 1)/KS) + 3) & ~3;
  int kbeg = ks*Kc, kend = min(Ktot, kbeg + Kc);
  int tm = tid >> 4, tn = tid & 15;
  float acc[4][4];
  #pragma unroll
  for (int i=0;i<4;i++){ acc[i][0]=0.f; acc[i][1]=0.f; acc[i][2]=0.f; acc[i][3]=0.f; }

  for (int k0 = kbeg; k0 < kend; k0 += 32){
    int klim = kend - k0; if (klim > 32) klim = 32;
    #pragma unroll
    for (int i=0;i<2;i++){
      int idx = tid + i*256;
      int m = idx >> 3, kq = (idx & 7) << 2;
      if (kq < klim){
        const float* ap = A + (size_t)(mb+m)*lda + k0 + kq;
        float4 v;
        if (kq + 3 < klim) v = *(const float4*)ap;
        else { v.x=ap[0]; v.y=(kq+1<klim)?ap[1]:0.f; v.z=(kq+2<klim)?ap[2]:0.f; v.w=0.f; }
        float* as = As + m;
        as[(kq+0)*68]=v.x; as[(kq+1)*68]=v.y; as[(kq+2)*68]=v.z; as[(kq+3)*68]=v.w;
      }
    }
    #pragma unroll
    for (int i=0;i<2;i++){
      int idx = tid + i*256;
      int kk = idx >> 4, nq = (idx & 15) << 2;
      int n = nb + nq;
      float4 v = {0.f,0.f,0.f,0.f};
      if (kk < klim && n < N){
        const float* bp = B + (size_t)(k0+kk)*N + n;
        if (n + 3 < N) v = *(const float4*)bp;
        else { v.x=bp[0]; v.y=(n+1<N)?bp[1]:0.f; v.z=(n+2<N)?bp[2]:0.f; }
      }
      *(float4*)(Bs + kk*68 + nq) = v;
    }
    __syncthreads();
    for (int kk = 0; kk < klim; kk++){
      float4 a = *(const float4*)(As + kk*68 + tm*4);
      float4 bv = *(const float4*)(Bs + kk*68 + tn*4);
      acc[0][0]+=a.x*bv.x; acc[0][1]+=a.x*bv.y; acc[0][2]+=a.x*bv.z; acc[0][3]+=a.x*bv.w;
      acc[1][0]+=a.y*bv.x; acc[1][1]+=a.y*bv.y; acc[1][2]+=a.y*bv.z; acc[1][3]+=a.y*bv.w;
      acc[2][0]+=a.z*bv.x; acc[2][1]+=a.z*bv.y; acc[2][2]+=a.z*bv.z; acc[2][3]+=a.z*bv.w;
      acc[3][0]+=a.w*bv.x; acc[3][1]+=a.w*bv.y; acc[3][2]+=a.w*bv.z; acc[3][3]+=a.w*bv.w;
    }
    __syncthreads();
  }

  #pragma unroll
  for (int i=0;i<4;i++){
    int m = tm*4 + i;
    #pragma unroll
    for (int j=0;j<4;j++){
      int n = nb + tn*4 + j;
      if (n < N){
        if (mode == 0){
          part[((size_t)(ks*64 + m))*N + n] = acc[i][j];
        } else {
          float v = acc[i][j] + (bias ? bias[n] : 0.f);
          if (mode == 2) v = tanhf(v);
          out[(size_t)(mb+m)*N + n] = v;
        }
      }
    }
  }
}

__global__ void reduce64(const float* __restrict__ part, int KS, int MN4, int N,
                         const float* __restrict__ bias, float* __restrict__ out, int mode){
  int idx = blockIdx.x*256 + threadIdx.x;
  if (idx >= MN4) return;
  int base = idx*4;
  int n = base % N;
  float4 s = {0.f,0.f,0.f,0.f};
  size_t stride = (size_t)MN4*4;
  for (int p=0;p<KS;p++){
    float4 t = *(const float4*)(part + (size_t)p*stride + base);
    s.x+=t.x; s.y+=t.y; s.z+=t.z; s.w+=t.w;
  }
  if (bias){
    float4 bb = *(const float4*)(bias + n);
    s.x+=bb.x; s.y+=bb.y; s.z+=bb.z; s.w+=bb.w;
  }
  if (mode == 1){ s.x=tanhf(s.x); s.y=tanhf(s.y); s.z=tanhf(s.z); s.w=tanhf(s.w); }
  *(float4*)(out + base) = s;
}

__global__ __launch_bounds__(256) void comb_kernel(const float* __restrict__ imgf,
                                                   const float* __restrict__ qsum,
                                                   float* __restrict__ comb){
  __shared__ float s_red[4];
  int b = blockIdx.x, tid = threadIdx.x;
  float ss = 0.f;
  for (int j = tid; j < 1024; j += 256){ float v = imgf[b*1024+j]; ss += v*v; }
  ss = wave_sum64(ss);
  if ((tid & 63) == 0) s_red[tid>>6] = ss;
  __syncthreads();
  float inv = 1.0f / sqrtf(s_red[0]+s_red[1]+s_red[2]+s_red[3]);
  for (int j = tid; j < 1024; j += 256)
    comb[b*1024+j] = tanhf(imgf[b*1024+j]*inv * qsum[b*1024+j]*0.05f);
}

__global__ void tanhrvec_kernel(const float* __restrict__ rvecT, float* __restrict__ lastB){
  int idx = blockIdx.x*256 + threadIdx.x;
  if (idx >= 16384) return;
  int b = idx & 63, i = idx >> 6;
  lastB[(size_t)b*1280 + 1024 + i] = tanhf(rvecT[i*64 + b]);
}

// ===================== persistent DNC recurrence kernel ===========================
struct SD_t {
  float s_rk[256], s_rstr[4], s_wkey[64], s_erase[64], s_wvec[64];
  float s_free[4], s_modes[12], s_scal[3];
  float s_wr[1024];
  float s_wwnew[256], s_usage[256], s_prec[256], s_scan[256], s_sim[256];
  float s_C[1024], s_D[1024];
  float s_red[4], s_PQ[8];
};
struct SGLO_t { float A[4096]; float g[512]; };
struct Shm {
  float Wg[768*8];   // 24 KB: gates weight slice (8 cols), persistent
  float Wo[768*4];   // 12 KB: out weight slice (4 cols), persistent
  float Wi[512*4];   //  8 KB: interface weight slice (4 cols), persistent
  union { SGLO_t glo; SD_t d; } u;
};

// hierarchical grid barrier: arrive via 16 sub-counters -> root -> gen flag; poll gen (loads only)
__device__ __forceinline__ void gbar(int* subs, int* root, int* gen, int epoch){
  __syncthreads();
  if (threadIdx.x == 0){
    __threadfence();
    int g = blockIdx.x & 15;
    int old = __hip_atomic_fetch_add(&subs[g*32], 1, __ATOMIC_RELAXED, __HIP_MEMORY_SCOPE_AGENT);
    if (old == 16*epoch - 1){
      int r = __hip_atomic_fetch_add(root, 1, __ATOMIC_RELAXED, __HIP_MEMORY_SCOPE_AGENT);
      if (r == 16*epoch - 1)
        __hip_atomic_store(gen, epoch, __ATOMIC_RELEASE, __HIP_MEMORY_SCOPE_AGENT);
    }
    while (__hip_atomic_load(gen, __ATOMIC_ACQUIRE, __HIP_MEMORY_SCOPE_AGENT) < epoch)
      __builtin_amdgcn_s_sleep(2);
    __threadfence();
  }
  __syncthreads();
}

// chunked out-GEMV: col = bid*4+q_, K = [hc(512) | rvec(256)]
__device__ __forceinline__ float chunkO(Shm& sh, const float* __restrict__ hcT_p,
                                        const float* __restrict__ rvecT,
                                        float bo, int b_, int q_, int tid){
  float acc = bo;
  for (int ch = 0; ch < 12; ch++){
    const float4* src = (const float4*)((ch < 8) ? (hcT_p + ch*4096) : (rvecT + (ch-8)*4096));
    float4* dst = (float4*)sh.u.glo.A;
    #pragma unroll
    for (int i = 0; i < 4; i++) dst[tid + i*256] = src[tid + i*256];
    __syncthreads();
    #pragma unroll 8
    for (int kk = 0; kk < 64; kk++)
      acc += sh.u.glo.A[kk*64 + b_] * sh.Wo[(ch*64+kk)*4 + q_];
    __syncthreads();
  }
  return clipf_(acc);
}

__global__ __launch_bounds__(256) void dnc_recur(
    int T, int outmode,
    const float* __restrict__ gxp, const float* __restrict__ Wih_r,
    const float* __restrict__ Whh, const float* __restrict__ gb,
    const float* __restrict__ Wif, const float* __restrict__ bif,
    const float* __restrict__ Wout, const float* __restrict__ bout,
    float* __restrict__ ws, float* __restrict__ outbuf, int* __restrict__ barmem)
{
  __shared__ Shm sh;

  float* memS  = ws + WS_MEM;
  float* linkS = ws + WS_LINK;
  float* precB = ws + WS_PREC;
  float* wrS   = ws + WS_WR;
  float* wwS   = ws + WS_WW;
  float* usgS  = ws + WS_USAGE;
  float* rvecT = ws + WS_RVECT;
  float* hT    = ws + WS_HT;
  float* hcT   = ws + WS_HCT;
  float* xiS   = ws + WS_XI;
  int* subs = barmem;
  int* root = barmem + 16*32;
  int* gen  = barmem + 16*32 + 32;

  int tid = threadIdx.x, bid = blockIdx.x;
  int lane = tid & 63, wid = tid >> 6;
  int b_ = tid & 63, q_ = tid >> 6;

  // ---- load persistent weight slices into LDS (once) ----
  {
    int c2 = bid*2;
    float2* Wg2 = (float2*)sh.Wg;
    for (int e2 = tid; e2 < 3072; e2 += 256){
      int k = e2 >> 2, g = e2 & 3;
      const float* src = (k < 256) ? (Wih_r + (size_t)k*2048 + g*512 + c2)
                                   : (Whh + (size_t)(k-256)*2048 + g*512 + c2);
      Wg2[e2] = *(const float2*)src;
    }
    int c4o = bid*4;
    float4* Wo4 = (float4*)sh.Wo;
    for (int k = tid; k < 768; k += 256)
      Wo4[k] = *(const float4*)(Wout + (size_t)k*1024 + c4o);
    if (bid < 118){
      for (int e = tid; e < 2048; e += 256){
        int k = e >> 2, c = e & 3;
        int col = c4o + c;
        sh.Wi[e] = (col < 471) ? Wif[(size_t)k*471 + col] : 0.f;
      }
    }
  }
  float bo = bout[bid*4 + q_];
  float bifv = 0.f;
  if (bid < 118 && bid*4 + q_ < 471) bifv = bif[bid*4 + q_];
  __syncthreads();

  float c_reg = 0.f;   // LSTM cell state (b_, col=bid*2+q_) for tid<128
  float qacc = 0.f;
  int epoch = 0;

  for (int t = 0; t < T; t++){
    int pp = t & 1, wp = (t + 1) & 1;

    // ======== phase GLO: O(t-1) + gates(t) + LSTM(t) ========
    if (t > 0){
      float v = chunkO(sh, hcT + pp*32768, rvecT, bo, b_, q_, tid);
      qacc += v;
    }
    {
      int n0 = q_*512 + bid*2;
      float2 gv = *(const float2*)(gxp + ((size_t)(t*64 + b_))*2048 + n0);
      float acc0 = gb[n0] + gv.x;
      float acc1 = gb[n0+1] + gv.y;
      const float* hT_p = hT + pp*32768;
      const float2* Wg2 = (const float2*)sh.Wg;
      for (int ch = 0; ch < 12; ch++){
        const float4* src = (const float4*)((ch < 4) ? (rvecT + ch*4096) : (hT_p + (ch-4)*4096));
        float4* dst = (float4*)sh.u.glo.A;
        #pragma unroll
        for (int i = 0; i < 4; i++) dst[tid + i*256] = src[tid + i*256];
        __syncthreads();
        #pragma unroll 8
        for (int kk = 0; kk < 64; kk++){
          float a = sh.u.glo.A[kk*64 + b_];
          float2 w = Wg2[(ch*64+kk)*4 + q_];
          acc0 += a*w.x; acc1 += a*w.y;
        }
        __syncthreads();
      }
      sh.u.glo.g[b_*8 + q_*2 + 0] = acc0;
      sh.u.glo.g[b_*8 + q_*2 + 1] = acc1;
      __syncthreads();
      if (tid < 128){
        int jj = q_;
        float gi = sh.u.glo.g[b_*8 + 0 + jj], gf = sh.u.glo.g[b_*8 + 2 + jj];
        float gg = sh.u.glo.g[b_*8 + 4 + jj], go = sh.u.glo.g[b_*8 + 6 + jj];
        float cn = sigmoidf_(gf)*c_reg + sigmoidf_(gi)*tanhf(gg);
        float hn = sigmoidf_(go)*tanhf(cn);
        c_reg = cn;
        int col = bid*2 + jj;
        hT [wp*32768 + col*64 + b_] = hn;
        hcT[wp*32768 + col*64 + b_] = clipf_(hn);
      }
    }
    epoch++; gbar(subs, root, gen, epoch);

    // ======== phase I: xi = hc @ Wif + bif ========
    if (bid < 118){
      int col = bid*4 + q_;
      float acc = bifv;
      const float* hc_p = hcT + wp*32768;
      for (int ch = 0; ch < 8; ch++){
        const float4* src = (const float4*)(hc_p + ch*4096);
        float4* dst = (float4*)sh.u.glo.A;
        #pragma unroll
        for (int i = 0; i < 4; i++) dst[tid + i*256] = src[tid + i*256];
        __syncthreads();
        #pragma unroll 8
        for (int kk = 0; kk < 64; kk++)
          acc += sh.u.glo.A[kk*64 + b_] * sh.Wi[(ch*64+kk)*4 + q_];
        __syncthreads();
      }
      if (col < 471) xiS[b_*471 + col] = acc;
    }
    epoch++; gbar(subs, root, gen, epoch);

    // ======== phase D: DNC memory step (blocks 0..63) ========
    if (bid < 64){
      SD_t& sd = sh.u.d;
      int b = bid;
      const float* prec_in  = precB + pp*16384;
      float*       prec_out = precB + wp*16384;

      // ---- Stage 1: parse interface, load states ----
      const float* xrow = xiS + (size_t)b*471;
      for (int idx = tid; idx < 471; idx += 256){
        float v = xrow[idx];
        if (idx < 256)       sd.s_rk[idx] = tanhf(v);
        else if (idx < 260)  sd.s_rstr[idx-256] = softplusf_(v);
        else if (idx < 324)  sd.s_wkey[idx-260] = v;
        else if (idx == 324) sd.s_scal[0] = softplusf_(v);
        else if (idx < 389)  sd.s_erase[idx-325] = sigmoidf_(v);
        else if (idx < 453)  sd.s_wvec[idx-389] = tanhf(v);
        else if (idx < 457)  sd.s_free[idx-453] = sigmoidf_(v);
        else if (idx == 457) sd.s_scal[1] = sigmoidf_(v);
        else if (idx == 458) sd.s_scal[2] = sigmoidf_(v);
        else                 sd.s_modes[idx-459] = v;
      }
      for (int e = tid; e < 1024; e += 256){
        sd.s_wr[e] = wrS[(size_t)b*1024 + e];
        sd.s_C[e] = 0.f; sd.s_D[e] = 0.f;
      }
      float wwold = wwS[(size_t)b*256 + tid];
      sd.s_usage[tid] = usgS[(size_t)b*256 + tid];
      sd.s_prec[tid]  = prec_in[(size_t)b*256 + tid];
      __syncthreads();

      if (tid < 4){
        float m0 = sd.s_modes[tid*3], m1 = sd.s_modes[tid*3+1], m2 = sd.s_modes[tid*3+2];
        float mx = fmaxf(m0, fmaxf(m1,m2));
        float e0 = expf(m0-mx), e1 = expf(m1-mx), e2 = expf(m2-mx);
        float s = e0+e1+e2;
        sd.s_modes[tid*3] = e0/s; sd.s_modes[tid*3+1] = e1/s; sd.s_modes[tid*3+2] = e2/s;
      }
      {
        float k = sd.s_rk[wid*64 + lane];
        float ss = wave_sum64(k*k);
        sd.s_rk[wid*64 + lane] = k / (sqrtf(ss) + EPSV);
      }
      if (wid == 0){
        float k = sd.s_wkey[lane];
        float ss = wave_sum64(k*k);
        sd.s_wkey[lane] = k / (sqrtf(ss) + EPSV);
      }

      // ---- Stage 2: usage update ----
      {
        float psi = 1.f;
        #pragma unroll
        for (int r=0;r<4;r++) psi *= (1.f - sd.s_free[r]*sd.s_wr[r*256+tid]);
        float u = (sd.s_usage[tid] + wwold - sd.s_usage[tid]*wwold) * psi;
        sd.s_usage[tid] = u;
        usgS[(size_t)b*256 + tid] = u;
      }
      __syncthreads();

      // ---- Stage 3: stable ascending rank (register) ----
      int rank_r;
      {
        float u = sd.s_usage[tid];
        int rank = 0;
        for (int j=0;j<256;j++){
          float uj = sd.s_usage[j];
          rank += (uj < u) || (uj == u && j < tid);
        }
        rank_r = rank;
        sd.s_scan[rank] = u;
      }
      __syncthreads();

      // ---- Stage 4: inclusive product scan ----
      for (int off=1; off<256; off<<=1){
        float tv = (tid >= off) ? sd.s_scan[tid-off] : 1.f;
        __syncthreads();
        sd.s_scan[tid] *= tv;
        __syncthreads();
      }
      float alloc_r;
      {
        float u = sd.s_usage[tid];
        float cpe = (rank_r > 0) ? sd.s_scan[rank_r-1] : 1.f;
        alloc_r = (1.f - u) * cpe;
      }

      // ---- Stage 5: write-key cosine (row-per-thread) ----
      {
        const float4* Mrow = (const float4*)(memS + (size_t)b*16384 + (size_t)tid*64);
        float nrm2 = 0.f, dt = 0.f;
        #pragma unroll
        for (int c4 = 0; c4 < 16; c4++){
          float4 mv = Mrow[c4];
          int w0 = c4*4;
          nrm2 += mv.x*mv.x + mv.y*mv.y + mv.z*mv.z + mv.w*mv.w;
          dt += mv.x*sd.s_wkey[w0] + mv.y*sd.s_wkey[w0+1] + mv.z*sd.s_wkey[w0+2] + mv.w*sd.s_wkey[w0+3];
        }
        sd.s_sim[tid] = dt / (sqrtf(nrm2)+EPSV) * sd.s_scal[0];
      }
      __syncthreads();

      // ---- Stage 6: write softmax, ww, prec, P, Q ----
      {
        float v = sd.s_sim[tid];
        float mx = block_max256(v, sd.s_red);
        float e = expf(v - mx);
        float sm = block_sum256(e, sd.s_red);
        float cw = e / sm;
        float wwn = sd.s_scal[2] * (sd.s_scal[1]*alloc_r + (1.f - sd.s_scal[1])*cw);
        sd.s_wwnew[tid] = wwn;
        wwS[(size_t)b*256 + tid] = wwn;
        float wws = block_sum256(wwn, sd.s_red);
        prec_out[(size_t)b*256 + tid] = (1.f - wws)*sd.s_prec[tid] + wwn;
        #pragma unroll
        for (int r=0;r<4;r++){
          float pv  = block_sum256(sd.s_prec[tid]*sd.s_wr[r*256+tid], sd.s_red);
          float qv_ = block_sum256(wwn*sd.s_wr[r*256+tid], sd.s_red);
          if (tid == 0){ sd.s_PQ[r] = pv; sd.s_PQ[4+r] = qv_; }
        }
      }
      __syncthreads();

      // ---- Stage 8a: A,B row-sums vs OLD link (thread=row, vB on the fly) ----
      float aA[4] = {0,0,0,0}, aB[4] = {0,0,0,0};
      {
        const float4* Lrow = (const float4*)(linkS + (size_t)b*65536 + (size_t)tid*256);
        for (int c4 = 0; c4 < 64; c4++){
          float4 lv = Lrow[c4];
          int j = c4*4;
          float w0n = sd.s_wwnew[j], w1n = sd.s_wwnew[j+1], w2n = sd.s_wwnew[j+2], w3n = sd.s_wwnew[j+3];
          #pragma unroll
          for (int r=0;r<4;r++){
            float wr0 = sd.s_wr[r*256+j], wr1 = sd.s_wr[r*256+j+1];
            float wr2 = sd.s_wr[r*256+j+2], wr3 = sd.s_wr[r*256+j+3];
            aA[r] += lv.x*wr0 + lv.y*wr1 + lv.z*wr2 + lv.w*wr3;
            aB[r] += lv.x*(w0n*wr0) + lv.y*(w1n*wr1) + lv.z*(w2n*wr2) + lv.w*(w3n*wr3);
          }
        }
      }
      __syncthreads();

      // ---- Stage 8b: link update + C,D col-sums ----
      {
        int cg = tid & 63, ioff = tid >> 6;
        int j0 = cg*4;
        float wwj0 = sd.s_wwnew[j0], wwj1 = sd.s_wwnew[j0+1], wwj2 = sd.s_wwnew[j0+2], wwj3 = sd.s_wwnew[j0+3];
        float pj0 = sd.s_prec[j0], pj1 = sd.s_prec[j0+1], pj2 = sd.s_prec[j0+2], pj3 = sd.s_prec[j0+3];
        float cC[4][4] = {{0}}, cD[4][4] = {{0}};
        float4* Lb = (float4*)(linkS + (size_t)b*65536);
        for (int it = 0; it < 64; it++){
          int i = it*4 + ioff;
          float4 lv = Lb[(size_t)i*64 + cg];
          float wwi = sd.s_wwnew[i];
          float4 ln;
          ln.x = (1.f - wwi - wwj0)*lv.x + wwi*pj0;
          ln.y = (1.f - wwi - wwj1)*lv.y + wwi*pj1;
          ln.z = (1.f - wwi - wwj2)*lv.z + wwi*pj2;
          ln.w = (1.f - wwi - wwj3)*lv.w + wwi*pj3;
          if (i >= j0 && i < j0+4){
            if (i == j0)        ln.x = 0.f;
            else if (i == j0+1) ln.y = 0.f;
            else if (i == j0+2) ln.z = 0.f;
            else                ln.w = 0.f;
          }
          Lb[(size_t)i*64 + cg] = ln;
          float wwiv = wwi;
          #pragma unroll
          for (int r=0;r<4;r++){
            float wri = sd.s_wr[r*256+i];
            float vbi = wwiv*wri;
            cC[r][0] += lv.x*wri; cC[r][1] += lv.y*wri; cC[r][2] += lv.z*wri; cC[r][3] += lv.w*wri;
            cD[r][0] += lv.x*vbi; cD[r][1] += lv.y*vbi; cD[r][2] += lv.z*vbi; cD[r][3] += lv.w*vbi;
          }
        }
        for (int w=0; w<4; w++){
          if (ioff == w){
            #pragma unroll
            for (int r=0;r<4;r++){
              sd.s_C[r*256+j0+0] += cC[r][0]; sd.s_C[r*256+j0+1] += cC[r][1];
              sd.s_C[r*256+j0+2] += cC[r][2]; sd.s_C[r*256+j0+3] += cC[r][3];
              sd.s_D[r*256+j0+0] += cD[r][0]; sd.s_D[r*256+j0+1] += cD[r][1];
              sd.s_D[r*256+j0+2] += cD[r][2]; sd.s_D[r*256+j0+3] += cD[r][3];
            }
          }
          __syncthreads();
        }
      }

      // ---- Stage 7+9 merged: mem RMW + read-key dots (row-per-thread) ----
      float pr[4];
      {
        float4* Mrow = (float4*)(memS + (size_t)b*16384 + (size_t)tid*64);
        float wwn = sd.s_wwnew[tid];
        float nrm2 = 0.f, d0=0.f, d1=0.f, d2=0.f, d3=0.f;
        #pragma unroll
        for (int c4 = 0; c4 < 16; c4++){
          float4 mv = Mrow[c4];
          int w0 = c4*4;
          mv.x = mv.x*(1.f - wwn*sd.s_erase[w0+0]) + wwn*sd.s_wvec[w0+0];
          mv.y = mv.y*(1.f - wwn*sd.s_erase[w0+1]) + wwn*sd.s_wvec[w0+1];
          mv.z = mv.z*(1.f - wwn*sd.s_erase[w0+2]) + wwn*sd.s_wvec[w0+2];
          mv.w = mv.w*(1.f - wwn*sd.s_erase[w0+3]) + wwn*sd.s_wvec[w0+3];
          Mrow[c4] = mv;
          nrm2 += mv.x*mv.x + mv.y*mv.y + mv.z*mv.z + mv.w*mv.w;
          d0 += mv.x*sd.s_rk[w0] + mv.y*sd.s_rk[w0+1] + mv.z*sd.s_rk[w0+2] + mv.w*sd.s_rk[w0+3];
          d1 += mv.x*sd.s_rk[64+w0] + mv.y*sd.s_rk[64+w0+1] + mv.z*sd.s_rk[64+w0+2] + mv.w*sd.s_rk[64+w0+3];
          d2 += mv.x*sd.s_rk[128+w0] + mv.y*sd.s_rk[128+w0+1] + mv.z*sd.s_rk[128+w0+2] + mv.w*sd.s_rk[128+w0+3];
          d3 += mv.x*sd.s_rk[192+w0] + mv.y*sd.s_rk[192+w0+1] + mv.z*sd.s_rk[192+w0+2] + mv.w*sd.s_rk[192+w0+3];
        }
        float inv = 1.f/(sqrtf(nrm2)+EPSV);
        pr[0] = d0*inv*sd.s_rstr[0];
        pr[1] = d1*inv*sd.s_rstr[1];
        pr[2] = d2*inv*sd.s_rstr[2];
        pr[3] = d3*inv*sd.s_rstr[3];
      }
      // read softmax (values in registers)
      #pragma unroll
      for (int r=0;r<4;r++){
        float mx = block_max256(pr[r], sd.s_red);
        float e = expf(pr[r] - mx);
        float sm = block_sum256(e, sd.s_red);
        pr[r] = e/sm;
      }
      __syncthreads();

      // ---- Stage 10: fw/bw assembly + wr update (write into s_wr) ----
      {
        float wwn = sd.s_wwnew[tid], pn = sd.s_prec[tid];
        #pragma unroll
        for (int r=0;r<4;r++){
          float wro = sd.s_wr[r*256+tid];
          float fw  = (1.f-wwn)*aA[r] - aB[r] + wwn*(sd.s_PQ[r] - pn*wro);
          float bwv = (1.f-wwn)*sd.s_C[r*256+tid] - sd.s_D[r*256+tid] + pn*(sd.s_PQ[4+r] - wwn*wro);
          float wrn = sd.s_modes[r*3+0]*bwv + sd.s_modes[r*3+1]*pr[r] + sd.s_modes[r*3+2]*fw;
          wrS[(size_t)b*1024 + r*256 + tid] = wrn;
          sd.s_wr[r*256+tid] = wrn;
        }
      }
      __syncthreads();

      // ---- Stage 11: rvecT = (wr_new @ mem)^T ----
      {
        int r = tid >> 6, w = tid & 63;
        const float* Mb = memS + (size_t)b*16384;
        float acc = 0.f;
        for (int n=0; n<256; n++) acc += sd.s_wr[r*256+n]*Mb[(size_t)n*64 + w];
        rvecT[(r*64 + w)*64 + b] = acc;
      }
    }
    epoch++; gbar(subs, root, gen, epoch);
  }

  // ======== final O(T-1) ========
  {
    float v = chunkO(sh, hcT + (T&1)*32768, rvecT, bo, b_, q_, tid);
    if (outmode == 0){
      qacc += v;
      outbuf[(size_t)b_*1024 + (bid*4 + q_)] = qacc;
    } else {
      outbuf[(size_t)b_*1280 + (bid*4 + q_)] = tanhf(v);
    }
  }
}

// ======================================================================================
extern "C" void kernel_launch(void* const* d_in, const int* in_sizes, int n_in,
                              void* d_out, int out_size, void* d_ws, size_t ws_size,
                              hipStream_t stream) {
  const float* img_feat = (const float*)d_in[0];
  const int*   qst      = (const int*)  d_in[1];
  const float* emb      = (const float*)d_in[2];
  const float* img_W    = (const float*)d_in[3];
  const float* img_b    = (const float*)d_in[4];
  const float* q_Wih    = (const float*)d_in[5];
  const float* q_Whh    = (const float*)d_in[6];
  const float* q_b      = (const float*)d_in[7];
  const float* q_Wif    = (const float*)d_in[8];
  const float* q_bif    = (const float*)d_in[9];
  const float* q_Wout   = (const float*)d_in[10];
  const float* q_bout   = (const float*)d_in[11];
  const float* c_Wih    = (const float*)d_in[12];
  const float* c_Whh    = (const float*)d_in[13];
  const float* c_b      = (const float*)d_in[14];
  const float* c_Wif    = (const float*)d_in[15];
  const float* c_bif    = (const float*)d_in[16];
  const float* c_Wout   = (const float*)d_in[17];
  const float* c_bout   = (const float*)d_in[18];
  const float* fc1_W    = (const float*)d_in[19];
  const float* fc1_b    = (const float*)d_in[20];
  const float* fc2_W    = (const float*)d_in[21];
  const float* fc2_b    = (const float*)d_in[22];

  float* ws = (float*)d_ws;
  float* qv    = ws + WS_QV;
  float* zoneC = ws + WS_ZONEC;
  float* imgf  = ws + WS_IMGF;
  float* combB = ws + WS_COMB;
  float* lastB = ws + WS_LASTB;
  float* hid1  = ws + WS_HID1;
  float* qsum  = ws + WS_QSUM;
  int*   bar   = (int*)(ws + WS_BAR);

  // zero state zone (incl. barrier counters, qsum)
  hipMemsetAsync(ws, 0, (size_t)WS_ZONEA*4, stream);

  // qv[(t*64+b)][300] = tanh(emb[qst])
  embed_kernel<<<1500, 256, 0, stream>>>(qst, emb, qv);

  // image fc: imgf = img_feat @ img_W + img_b  (split-K 16)
  gemm64<<<dim3(16,16,1), 256, 0, stream>>>(64, 1024, 4096, 16,
      img_feat, 4096, img_W, nullptr, nullptr, zoneC, 0);
  reduce64<<<64, 256, 0, stream>>>(zoneC, 16, 16384, 1024, img_b, imgf, 0);

  // gxp = qv @ q_Wih[0:300]
  gemm64<<<dim3(32,1,20), 256, 0, stream>>>(1280, 2048, 300, 1,
      qv, 300, q_Wih, nullptr, zoneC, nullptr, 1);

  // question DNC, 20 steps (persistent)
  dnc_recur<<<256, 256, 0, stream>>>(20, 0,
      zoneC, q_Wih + (size_t)300*2048, q_Whh, q_b,
      q_Wif, q_bif, q_Wout, q_bout, ws, qsum, bar);

  // comb = tanh(l2norm(imgf) * qsum/20)
  comb_kernel<<<64, 256, 0, stream>>>(imgf, qsum, combB);

  // reset state zone for controller
  hipMemsetAsync(ws, 0, (size_t)WS_ZONEA*4, stream);

  // cxp = comb @ c_Wih[0:1024]  (split-K 4)
  float* cxp  = zoneC;
  float* cxpP = zoneC + 131072;
  gemm64<<<dim3(32,4,1), 256, 0, stream>>>(64, 2048, 1024, 4,
      combB, 1024, c_Wih, nullptr, nullptr, cxpP, 0);
  reduce64<<<128, 256, 0, stream>>>(cxpP, 4, 32768, 2048, nullptr, cxp, 0);

  // controller DNC, 1 step (persistent) -> lastB[:, :1024]
  dnc_recur<<<256, 256, 0, stream>>>(1, 1,
      cxp, c_Wih + (size_t)1024*2048, c_Whh, c_b,
      c_Wif, c_bif, c_Wout, c_bout, ws, lastB, bar);

  // lastB[:, 1024:1280] = tanh(rvec_ctrl)
  tanhrvec_kernel<<<64, 256, 0, stream>>>(ws + WS_RVECT, lastB);

  // fc1: hid1 = tanh(lastB @ fc1_W + fc1_b)  (split-K 5)
  gemm64<<<dim3(47,5,1), 256, 0, stream>>>(64, 3000, 1280, 5,
      lastB, 1280, fc1_W, nullptr, nullptr, zoneC, 0);
  reduce64<<<188, 256, 0, stream>>>(zoneC, 5, 48000, 3000, fc1_b, hid1, 1);

  // fc2: logits = hid1 @ fc2_W + fc2_b  (split-K 6)
  gemm64<<<dim3(47,6,1), 256, 0, stream>>>(64, 3000, 3000, 6,
      hid1, 3000, fc2_W, nullptr, nullptr, zoneC, 0);
  reduce64<<<188, 256, 0, stream>>>(zoneC, 6, 48000, 3000, fc2_b, (float*)d_out, 0);
}

// Round 4
// 2598.007 us; speedup vs baseline: 2.8531x; 2.8531x over previous
//
#include <hip/hip_runtime.h>
#include <cmath>

#define CLIPV 20.0f
#define EPSV 1e-6f

__device__ __forceinline__ float sigmoidf_(float x){ return 1.0f/(1.0f + expf(-x)); }
__device__ __forceinline__ float softplusf_(float x){ return (x > 20.0f) ? x : log1pf(expf(x)); }
__device__ __forceinline__ float clipf_(float x){ return fminf(fmaxf(x, -CLIPV), CLIPV); }

__device__ __forceinline__ float wave_sum64(float v){
  #pragma unroll
  for (int off=32; off>=1; off>>=1) v += __shfl_xor(v, off, 64);
  return v;
}
__device__ __forceinline__ float wave_max64(float v){
  #pragma unroll
  for (int off=32; off>=1; off>>=1) v = fmaxf(v, __shfl_xor(v, off, 64));
  return v;
}
__device__ __forceinline__ float block_sum256(float v, float* s_red){
  v = wave_sum64(v);
  __syncthreads();
  if ((threadIdx.x & 63) == 0) s_red[threadIdx.x>>6] = v;
  __syncthreads();
  return s_red[0]+s_red[1]+s_red[2]+s_red[3];
}
__device__ __forceinline__ float block_max256(float v, float* s_red){
  v = wave_max64(v);
  __syncthreads();
  if ((threadIdx.x & 63) == 0) s_red[threadIdx.x>>6] = v;
  __syncthreads();
  return fmaxf(fmaxf(s_red[0],s_red[1]), fmaxf(s_red[2],s_red[3]));
}

// write-through store to coherence point (no cache maintenance)
__device__ __forceinline__ void cstore(float* p, float v){
  __hip_atomic_store(p, v, __ATOMIC_RELAXED, __HIP_MEMORY_SCOPE_AGENT);
}

// ---- workspace layout (float offsets) ----
#define WS_MEM    0          /* 1,048,576 */
#define WS_LINK   1048576    /* 4,194,304 */
#define WS_PREC   5242880    /* 2 x 16384 */
#define WS_WR     5275648    /* 65,536 */
#define WS_WW     5341184    /* 16,384 */
#define WS_USAGE  5357568    /* 16,384 */
#define WS_BAR    5373952    /* 1024 ints */
#define WS_ZONEA  5374976    /* memset extent */
#define WS_QSUM   5374976    /* 65,536 (init not required) */
#define WS_HTS    5440512    /* 21 x 32768 h slots */
#define WS_RVS    6128640    /* 21 x 16384 rvecT slots */
#define WS_XIS    6472704    /* 21 x 30144 xi slots */
#define WS_GXP    7105728    /* 2,621,440 (q gxp; c cxp) */
#define WS_ZONEC  9727168    /* 1,152,000 gemm partials */
#define WS_IMGF   10879168
#define WS_COMB   10944704
#define WS_LASTB  11010240   /* [64][1280] */
#define WS_HID1   11092160   /* [64][3000] */
#define WS_QV     11284160   /* [1280][300] */

// ------------------------- embedding -------------------------
__global__ void embed_kernel(const int* __restrict__ qst, const float* __restrict__ emb,
                             float* __restrict__ qv){
  int idx = blockIdx.x*256 + threadIdx.x;
  if (idx >= 1280*300) return;
  int m = idx / 300;
  int e = idx - m*300;
  int t = m >> 6, b = m & 63;
  int tok = qst[b*20 + t];
  qv[idx] = tanhf(emb[(size_t)tok*300 + e]);
}

// ------------------------- generic tiled f32 GEMM (float4 loads) ------------------
__global__ __launch_bounds__(256) void gemm64(
    int M, int N, int Ktot, int KS,
    const float* __restrict__ A, int lda,
    const float* __restrict__ B,
    const float* __restrict__ bias,
    float* __restrict__ out, float* __restrict__ part, int mode)
{
  __shared__ float As[32*68];
  __shared__ float Bs[32*68];
  int tid = threadIdx.x;
  int nb = blockIdx.x*64, ks = blockIdx.y, mb = blockIdx.z*64;
  int Kc = (((Ktot + KS - 1)/KS) + 3) & ~3;
  int kbeg = ks*Kc, kend = min(Ktot, kbeg + Kc);
  int tm = tid >> 4, tn = tid & 15;
  float acc[4][4];
  #pragma unroll
  for (int i=0;i<4;i++){ acc[i][0]=0.f; acc[i][1]=0.f; acc[i][2]=0.f; acc[i][3]=0.f; }

  for (int k0 = kbeg; k0 < kend; k0 += 32){
    int klim = kend - k0; if (klim > 32) klim = 32;
    #pragma unroll
    for (int i=0;i<2;i++){
      int idx = tid + i*256;
      int m = idx >> 3, kq = (idx & 7) << 2;
      if (kq < klim){
        const float* ap = A + (size_t)(mb+m)*lda + k0 + kq;
        float4 v;
        if (kq + 3 < klim) v = *(const float4*)ap;
        else { v.x=ap[0]; v.y=(kq+1<klim)?ap[1]:0.f; v.z=(kq+2<klim)?ap[2]:0.f; v.w=0.f; }
        float* as = As + m;
        as[(kq+0)*68]=v.x; as[(kq+1)*68]=v.y; as[(kq+2)*68]=v.z; as[(kq+3)*68]=v.w;
      }
    }
    #pragma unroll
    for (int i=0;i<2;i++){
      int idx = tid + i*256;
      int kk = idx >> 4, nq = (idx & 15) << 2;
      int n = nb + nq;
      float4 v = {0.f,0.f,0.f,0.f};
      if (kk < klim && n < N){
        const float* bp = B + (size_t)(k0+kk)*N + n;
        if (n + 3 < N) v = *(const float4*)bp;
        else { v.x=bp[0]; v.y=(n+1<N)?bp[1]:0.f; v.z=(n+2<N)?bp[2]:0.f; }
      }
      *(float4*)(Bs + kk*68 + nq) = v;
    }
    __syncthreads();
    for (int kk = 0; kk < klim; kk++){
      float4 a = *(const float4*)(As + kk*68 + tm*4);
      float4 bv = *(const float4*)(Bs + kk*68 + tn*4);
      acc[0][0]+=a.x*bv.x; acc[0][1]+=a.x*bv.y; acc[0][2]+=a.x*bv.z; acc[0][3]+=a.x*bv.w;
      acc[1][0]+=a.y*bv.x; acc[1][1]+=a.y*bv.y; acc[1][2]+=a.y*bv.z; acc[1][3]+=a.y*bv.w;
      acc[2][0]+=a.z*bv.x; acc[2][1]+=a.z*bv.y; acc[2][2]+=a.z*bv.z; acc[2][3]+=a.z*bv.w;
      acc[3][0]+=a.w*bv.x; acc[3][1]+=a.w*bv.y; acc[3][2]+=a.w*bv.z; acc[3][3]+=a.w*bv.w;
    }
    __syncthreads();
  }

  #pragma unroll
  for (int i=0;i<4;i++){
    int m = tm*4 + i;
    #pragma unroll
    for (int j=0;j<4;j++){
      int n = nb + tn*4 + j;
      if (n < N){
        if (mode == 0){
          part[((size_t)(ks*64 + m))*N + n] = acc[i][j];
        } else {
          float v = acc[i][j] + (bias ? bias[n] : 0.f);
          if (mode == 2) v = tanhf(v);
          out[(size_t)(mb+m)*N + n] = v;
        }
      }
    }
  }
}

__global__ void reduce64(const float* __restrict__ part, int KS, int MN4, int N,
                         const float* __restrict__ bias, float* __restrict__ out, int mode){
  int idx = blockIdx.x*256 + threadIdx.x;
  if (idx >= MN4) return;
  int base = idx*4;
  int n = base % N;
  float4 s = {0.f,0.f,0.f,0.f};
  size_t stride = (size_t)MN4*4;
  for (int p=0;p<KS;p++){
    float4 t = *(const float4*)(part + (size_t)p*stride + base);
    s.x+=t.x; s.y+=t.y; s.z+=t.z; s.w+=t.w;
  }
  if (bias){
    float4 bb = *(const float4*)(bias + n);
    s.x+=bb.x; s.y+=bb.y; s.z+=bb.z; s.w+=bb.w;
  }
  if (mode == 1){ s.x=tanhf(s.x); s.y=tanhf(s.y); s.z=tanhf(s.z); s.w=tanhf(s.w); }
  *(float4*)(out + base) = s;
}

__global__ __launch_bounds__(256) void comb_kernel(const float* __restrict__ imgf,
                                                   const float* __restrict__ qsum,
                                                   float* __restrict__ comb){
  __shared__ float s_red[4];
  int b = blockIdx.x, tid = threadIdx.x;
  float ss = 0.f;
  for (int j = tid; j < 1024; j += 256){ float v = imgf[b*1024+j]; ss += v*v; }
  ss = wave_sum64(ss);
  if ((tid & 63) == 0) s_red[tid>>6] = ss;
  __syncthreads();
  float inv = 1.0f / sqrtf(s_red[0]+s_red[1]+s_red[2]+s_red[3]);
  for (int j = tid; j < 1024; j += 256)
    comb[b*1024+j] = tanhf(imgf[b*1024+j]*inv * qsum[b*1024+j]*0.05f);
}

__global__ void tanhrvec_kernel(const float* __restrict__ rvecT, float* __restrict__ lastB){
  int idx = blockIdx.x*256 + threadIdx.x;
  if (idx >= 16384) return;
  int b = idx & 63, i = idx >> 6;
  lastB[(size_t)b*1280 + 1024 + i] = tanhf(rvecT[i*64 + b]);
}

// ===================== persistent DNC recurrence kernel ===========================
struct SD_t {
  float s_rk[256], s_rstr[4], s_wkey[64], s_erase[64], s_wvec[64];
  float s_free[4], s_modes[12], s_scal[3];
  float s_wr[1024];
  float s_wwnew[256], s_usage[256], s_prec[256], s_scan[256], s_sim[256];
  float s_C[1024], s_D[1024];
  float s_red[4], s_PQ[8];
};
struct SGLO_t { float A[4096]; float g[512]; };
struct Shm {
  float Wg[768*8];   // 24 KB: gates recurrent-weight slice (8 cols), persistent
  float Wo[768*4];   // 12 KB: out weight slice (4 cols), persistent
  float Wi[512*4];   //  8 KB: interface weight slice (4 cols), persistent
  union { SGLO_t glo; SD_t d; } u;
};

// fence-free hierarchical grid barrier: relaxed atomics only, no cache maintenance
__device__ __forceinline__ void gbar(int* subs, int* root, int* gen, int epoch){
  __syncthreads();
  if (threadIdx.x == 0){
    asm volatile("s_waitcnt vmcnt(0)" ::: "memory");
    int g = blockIdx.x & 15;
    int old = __hip_atomic_fetch_add(&subs[g*32], 1, __ATOMIC_RELAXED, __HIP_MEMORY_SCOPE_AGENT);
    if (old == 16*epoch - 1){
      int r = __hip_atomic_fetch_add(root, 1, __ATOMIC_RELAXED, __HIP_MEMORY_SCOPE_AGENT);
      if (r == 16*epoch - 1)
        __hip_atomic_store(gen, epoch, __ATOMIC_RELAXED, __HIP_MEMORY_SCOPE_AGENT);
    }
    while (__hip_atomic_load(gen, __ATOMIC_RELAXED, __HIP_MEMORY_SCOPE_AGENT) < epoch)
      __builtin_amdgcn_s_sleep(2);
    asm volatile("" ::: "memory");
  }
  __syncthreads();
}

__global__ __launch_bounds__(256) void dnc_recur(
    int T, int outmode, int slot0,
    const float* __restrict__ xpart, const float* __restrict__ Wih_r,
    const float* __restrict__ Whh, const float* __restrict__ gb,
    const float* __restrict__ Wif, const float* __restrict__ bif,
    const float* __restrict__ Wout, const float* __restrict__ bout,
    float* __restrict__ ws, float* __restrict__ outbuf, int* __restrict__ barmem)
{
  __shared__ Shm sh;

  float* memS  = ws + WS_MEM;
  float* linkS = ws + WS_LINK;
  float* precB = ws + WS_PREC;
  float* wrS   = ws + WS_WR;
  float* wwS   = ws + WS_WW;
  float* usgS  = ws + WS_USAGE;
  float* htS   = ws + WS_HTS;
  float* rvS   = ws + WS_RVS;
  float* xiSl  = ws + WS_XIS;
  int* subs = barmem;
  int* root = barmem + 16*32;
  int* gen  = barmem + 16*32 + 32;

  int tid = threadIdx.x, bid = blockIdx.x;
  int lane = tid & 63, wid = tid >> 6;
  int b_ = tid & 63, q_ = tid >> 6;

  // ---- load persistent weight slices into LDS (once) ----
  {
    int c2 = bid*2;
    float2* Wg2w = (float2*)sh.Wg;
    for (int e2 = tid; e2 < 3072; e2 += 256){
      int k = e2 >> 2, g = e2 & 3;
      const float* src = (k < 256) ? (Wih_r + (size_t)k*2048 + g*512 + c2)
                                   : (Whh + (size_t)(k-256)*2048 + g*512 + c2);
      Wg2w[e2] = *(const float2*)src;
    }
    int c4o = bid*4;
    float4* Wo4 = (float4*)sh.Wo;
    for (int k = tid; k < 768; k += 256)
      Wo4[k] = *(const float4*)(Wout + (size_t)k*1024 + c4o);
    if (bid < 118){
      for (int e = tid; e < 2048; e += 256){
        int k = e >> 2, c = e & 3;
        int col = c4o + c;
        sh.Wi[e] = (col < 471) ? Wif[(size_t)k*471 + col] : 0.f;
      }
    }
  }
  float bo = bout[bid*4 + q_];
  float bifv = 0.f;
  if (bid < 118 && bid*4 + q_ < 471) bifv = bif[bid*4 + q_];
  __syncthreads();

  float c_reg = 0.f;   // LSTM cell state (b_, col=bid*2+q_) for tid<128
  float qacc = 0.f;
  int epoch = 0;

  for (int t = 0; t < T; t++){
    int pp = t & 1, wp = (t + 1) & 1;

    // ======== phase GLO: O(t-1) + gates(t) + LSTM(t) ========
    {
      int n0 = q_*512 + bid*2;
      float2 gv = *(const float2*)(xpart + ((size_t)(t*64 + b_))*2048 + n0);
      float acc0 = gb[n0] + gv.x;
      float acc1 = gb[n0+1] + gv.y;
      if (t > 0){
        float accO = bo;
        const float* rvP = rvS + (size_t)(slot0+t-1)*16384;
        const float* hP  = htS + (size_t)(slot0+t-1)*32768;
        const float2* Wg2 = (const float2*)sh.Wg;
        float4 pf[4];
        { const float4* s = (const float4*)rvP;
          #pragma unroll
          for (int i=0;i<4;i++) pf[i] = s[tid + i*256]; }
        for (int c = 0; c < 12; c++){
          __syncthreads();
          { float4* d = (float4*)sh.u.glo.A;
            #pragma unroll
            for (int i=0;i<4;i++) d[tid + i*256] = pf[i]; }
          if (c < 11){
            const float4* s = (const float4*)((c < 3) ? (rvP + (c+1)*4096) : (hP + (c-3)*4096));
            #pragma unroll
            for (int i=0;i<4;i++) pf[i] = s[tid + i*256];
          }
          __syncthreads();
          if (c < 4){
            #pragma unroll 8
            for (int kk=0;kk<64;kk++){
              float a = sh.u.glo.A[kk*64 + b_];
              accO += a * sh.Wo[(512 + c*64 + kk)*4 + q_];
              float2 w = Wg2[(c*64+kk)*4 + q_];
              acc0 += a*w.x; acc1 += a*w.y;
            }
          } else {
            int r0 = (c-4)*64;
            #pragma unroll 8
            for (int kk=0;kk<64;kk++){
              float a = sh.u.glo.A[kk*64 + b_];
              float ac = clipf_(a);
              accO += ac * sh.Wo[(r0 + kk)*4 + q_];
              float2 w = Wg2[(256 + r0 + kk)*4 + q_];
              acc0 += a*w.x; acc1 += a*w.y;
            }
          }
        }
        qacc += clipf_(accO);
        __syncthreads();
      }
      sh.u.glo.g[b_*8 + q_*2 + 0] = acc0;
      sh.u.glo.g[b_*8 + q_*2 + 1] = acc1;
      __syncthreads();
      if (tid < 128){
        int jj = q_;
        float gi = sh.u.glo.g[b_*8 + 0 + jj], gf = sh.u.glo.g[b_*8 + 2 + jj];
        float gg = sh.u.glo.g[b_*8 + 4 + jj], go = sh.u.glo.g[b_*8 + 6 + jj];
        float cn = sigmoidf_(gf)*c_reg + sigmoidf_(gi)*tanhf(gg);
        float hn = sigmoidf_(go)*tanhf(cn);
        c_reg = cn;
        int col = bid*2 + jj;
        cstore(&htS[(size_t)(slot0+t)*32768 + col*64 + b_], hn);
      }
    }
    epoch++; gbar(subs, root, gen, epoch);

    // ======== phase I: xi = clip(h) @ Wif + bif ========
    if (bid < 118){
      int col = bid*4 + q_;
      float acc = bifv;
      const float* hP = htS + (size_t)(slot0+t)*32768;
      float4 pf[4];
      { const float4* s = (const float4*)hP;
        #pragma unroll
        for (int i=0;i<4;i++) pf[i] = s[tid + i*256]; }
      for (int c = 0; c < 8; c++){
        __syncthreads();
        { float4* d = (float4*)sh.u.glo.A;
          #pragma unroll
          for (int i=0;i<4;i++) d[tid + i*256] = pf[i]; }
        if (c < 7){
          const float4* s = (const float4*)(hP + (c+1)*4096);
          #pragma unroll
          for (int i=0;i<4;i++) pf[i] = s[tid + i*256];
        }
        __syncthreads();
        #pragma unroll 8
        for (int kk=0;kk<64;kk++)
          acc += clipf_(sh.u.glo.A[kk*64 + b_]) * sh.Wi[(c*64+kk)*4 + q_];
      }
      if (col < 471) cstore(&xiSl[(size_t)(slot0+t)*30144 + b_*471 + col], acc);
    }
    epoch++; gbar(subs, root, gen, epoch);

    // ======== phase D: DNC memory step (blocks 0..63) ========
    if (bid < 64){
      SD_t& sd = sh.u.d;
      int b = bid;
      const float* prec_in  = precB + pp*16384;
      float*       prec_out = precB + wp*16384;

      // ---- Stage 1: parse interface, load states ----
      const float* xrow = xiSl + (size_t)(slot0+t)*30144 + (size_t)b*471;
      for (int idx = tid; idx < 471; idx += 256){
        float v = xrow[idx];
        if (idx < 256)       sd.s_rk[idx] = tanhf(v);
        else if (idx < 260)  sd.s_rstr[idx-256] = softplusf_(v);
        else if (idx < 324)  sd.s_wkey[idx-260] = v;
        else if (idx == 324) sd.s_scal[0] = softplusf_(v);
        else if (idx < 389)  sd.s_erase[idx-325] = sigmoidf_(v);
        else if (idx < 453)  sd.s_wvec[idx-389] = tanhf(v);
        else if (idx < 457)  sd.s_free[idx-453] = sigmoidf_(v);
        else if (idx == 457) sd.s_scal[1] = sigmoidf_(v);
        else if (idx == 458) sd.s_scal[2] = sigmoidf_(v);
        else                 sd.s_modes[idx-459] = v;
      }
      for (int e = tid; e < 1024; e += 256){
        sd.s_wr[e] = wrS[(size_t)b*1024 + e];
        sd.s_C[e] = 0.f; sd.s_D[e] = 0.f;
      }
      float wwold = wwS[(size_t)b*256 + tid];
      sd.s_usage[tid] = usgS[(size_t)b*256 + tid];
      sd.s_prec[tid]  = prec_in[(size_t)b*256 + tid];
      __syncthreads();

      if (tid < 4){
        float m0 = sd.s_modes[tid*3], m1 = sd.s_modes[tid*3+1], m2 = sd.s_modes[tid*3+2];
        float mx = fmaxf(m0, fmaxf(m1,m2));
        float e0 = expf(m0-mx), e1 = expf(m1-mx), e2 = expf(m2-mx);
        float s = e0+e1+e2;
        sd.s_modes[tid*3] = e0/s; sd.s_modes[tid*3+1] = e1/s; sd.s_modes[tid*3+2] = e2/s;
      }
      {
        float k = sd.s_rk[wid*64 + lane];
        float ss = wave_sum64(k*k);
        sd.s_rk[wid*64 + lane] = k / (sqrtf(ss) + EPSV);
      }
      if (wid == 0){
        float k = sd.s_wkey[lane];
        float ss = wave_sum64(k*k);
        sd.s_wkey[lane] = k / (sqrtf(ss) + EPSV);
      }

      // ---- Stage 2: usage update ----
      {
        float psi = 1.f;
        #pragma unroll
        for (int r=0;r<4;r++) psi *= (1.f - sd.s_free[r]*sd.s_wr[r*256+tid]);
        float u = (sd.s_usage[tid] + wwold - sd.s_usage[tid]*wwold) * psi;
        sd.s_usage[tid] = u;
        usgS[(size_t)b*256 + tid] = u;
      }
      __syncthreads();

      // ---- Stage 3: stable ascending rank ----
      int rank_r;
      {
        float u = sd.s_usage[tid];
        int rank = 0;
        for (int j=0;j<256;j++){
          float uj = sd.s_usage[j];
          rank += (uj < u) || (uj == u && j < tid);
        }
        rank_r = rank;
        sd.s_scan[rank] = u;
      }
      __syncthreads();

      // ---- Stage 4: inclusive product scan ----
      for (int off=1; off<256; off<<=1){
        float tv = (tid >= off) ? sd.s_scan[tid-off] : 1.f;
        __syncthreads();
        sd.s_scan[tid] *= tv;
        __syncthreads();
      }
      float alloc_r;
      {
        float u = sd.s_usage[tid];
        float cpe = (rank_r > 0) ? sd.s_scan[rank_r-1] : 1.f;
        alloc_r = (1.f - u) * cpe;
      }

      // ---- Stage 5: write-key cosine (row-per-thread) ----
      {
        const float4* Mrow = (const float4*)(memS + (size_t)b*16384 + (size_t)tid*64);
        float nrm2 = 0.f, dt = 0.f;
        #pragma unroll
        for (int c4 = 0; c4 < 16; c4++){
          float4 mv = Mrow[c4];
          int w0 = c4*4;
          nrm2 += mv.x*mv.x + mv.y*mv.y + mv.z*mv.z + mv.w*mv.w;
          dt += mv.x*sd.s_wkey[w0] + mv.y*sd.s_wkey[w0+1] + mv.z*sd.s_wkey[w0+2] + mv.w*sd.s_wkey[w0+3];
        }
        sd.s_sim[tid] = dt / (sqrtf(nrm2)+EPSV) * sd.s_scal[0];
      }
      __syncthreads();

      // ---- Stage 6: write softmax, ww, prec, P, Q ----
      {
        float v = sd.s_sim[tid];
        float mx = block_max256(v, sd.s_red);
        float e = expf(v - mx);
        float sm = block_sum256(e, sd.s_red);
        float cw = e / sm;
        float wwn = sd.s_scal[2] * (sd.s_scal[1]*alloc_r + (1.f - sd.s_scal[1])*cw);
        sd.s_wwnew[tid] = wwn;
        wwS[(size_t)b*256 + tid] = wwn;
        float wws = block_sum256(wwn, sd.s_red);
        prec_out[(size_t)b*256 + tid] = (1.f - wws)*sd.s_prec[tid] + wwn;
        #pragma unroll
        for (int r=0;r<4;r++){
          float pv  = block_sum256(sd.s_prec[tid]*sd.s_wr[r*256+tid], sd.s_red);
          float qv_ = block_sum256(wwn*sd.s_wr[r*256+tid], sd.s_red);
          if (tid == 0){ sd.s_PQ[r] = pv; sd.s_PQ[4+r] = qv_; }
        }
      }
      __syncthreads();

      // ---- Stage 8a: A,B row-sums vs OLD link ----
      float aA[4] = {0,0,0,0}, aB[4] = {0,0,0,0};
      {
        const float4* Lrow = (const float4*)(linkS + (size_t)b*65536 + (size_t)tid*256);
        for (int c4 = 0; c4 < 64; c4++){
          float4 lv = Lrow[c4];
          int j = c4*4;
          float w0n = sd.s_wwnew[j], w1n = sd.s_wwnew[j+1], w2n = sd.s_wwnew[j+2], w3n = sd.s_wwnew[j+3];
          #pragma unroll
          for (int r=0;r<4;r++){
            float wr0 = sd.s_wr[r*256+j], wr1 = sd.s_wr[r*256+j+1];
            float wr2 = sd.s_wr[r*256+j+2], wr3 = sd.s_wr[r*256+j+3];
            aA[r] += lv.x*wr0 + lv.y*wr1 + lv.z*wr2 + lv.w*wr3;
            aB[r] += lv.x*(w0n*wr0) + lv.y*(w1n*wr1) + lv.z*(w2n*wr2) + lv.w*(w3n*wr3);
          }
        }
      }
      __syncthreads();

      // ---- Stage 8b: link update + C,D col-sums ----
      {
        int cg = tid & 63, ioff = tid >> 6;
        int j0 = cg*4;
        float wwj0 = sd.s_wwnew[j0], wwj1 = sd.s_wwnew[j0+1], wwj2 = sd.s_wwnew[j0+2], wwj3 = sd.s_wwnew[j0+3];
        float pj0 = sd.s_prec[j0], pj1 = sd.s_prec[j0+1], pj2 = sd.s_prec[j0+2], pj3 = sd.s_prec[j0+3];
        float cC[4][4] = {{0}}, cD[4][4] = {{0}};
        float4* Lb = (float4*)(linkS + (size_t)b*65536);
        for (int it = 0; it < 64; it++){
          int i = it*4 + ioff;
          float4 lv = Lb[(size_t)i*64 + cg];
          float wwi = sd.s_wwnew[i];
          float4 ln;
          ln.x = (1.f - wwi - wwj0)*lv.x + wwi*pj0;
          ln.y = (1.f - wwi - wwj1)*lv.y + wwi*pj1;
          ln.z = (1.f - wwi - wwj2)*lv.z + wwi*pj2;
          ln.w = (1.f - wwi - wwj3)*lv.w + wwi*pj3;
          if (i >= j0 && i < j0+4){
            if (i == j0)        ln.x = 0.f;
            else if (i == j0+1) ln.y = 0.f;
            else if (i == j0+2) ln.z = 0.f;
            else                ln.w = 0.f;
          }
          Lb[(size_t)i*64 + cg] = ln;
          #pragma unroll
          for (int r=0;r<4;r++){
            float wri = sd.s_wr[r*256+i];
            float vbi = wwi*wri;
            cC[r][0] += lv.x*wri; cC[r][1] += lv.y*wri; cC[r][2] += lv.z*wri; cC[r][3] += lv.w*wri;
            cD[r][0] += lv.x*vbi; cD[r][1] += lv.y*vbi; cD[r][2] += lv.z*vbi; cD[r][3] += lv.w*vbi;
          }
        }
        for (int w=0; w<4; w++){
          if (ioff == w){
            #pragma unroll
            for (int r=0;r<4;r++){
              sd.s_C[r*256+j0+0] += cC[r][0]; sd.s_C[r*256+j0+1] += cC[r][1];
              sd.s_C[r*256+j0+2] += cC[r][2]; sd.s_C[r*256+j0+3] += cC[r][3];
              sd.s_D[r*256+j0+0] += cD[r][0]; sd.s_D[r*256+j0+1] += cD[r][1];
              sd.s_D[r*256+j0+2] += cD[r][2]; sd.s_D[r*256+j0+3] += cD[r][3];
            }
          }
          __syncthreads();
        }
      }

      // ---- Stage 7+9 merged: mem RMW + read-key dots ----
      float pr[4];
      {
        float4* Mrow = (float4*)(memS + (size_t)b*16384 + (size_t)tid*64);
        float wwn = sd.s_wwnew[tid];
        float nrm2 = 0.f, d0=0.f, d1=0.f, d2=0.f, d3=0.f;
        #pragma unroll
        for (int c4 = 0; c4 < 16; c4++){
          float4 mv = Mrow[c4];
          int w0 = c4*4;
          mv.x = mv.x*(1.f - wwn*sd.s_erase[w0+0]) + wwn*sd.s_wvec[w0+0];
          mv.y = mv.y*(1.f - wwn*sd.s_erase[w0+1]) + wwn*sd.s_wvec[w0+1];
          mv.z = mv.z*(1.f - wwn*sd.s_erase[w0+2]) + wwn*sd.s_wvec[w0+2];
          mv.w = mv.w*(1.f - wwn*sd.s_erase[w0+3]) + wwn*sd.s_wvec[w0+3];
          Mrow[c4] = mv;
          nrm2 += mv.x*mv.x + mv.y*mv.y + mv.z*mv.z + mv.w*mv.w;
          d0 += mv.x*sd.s_rk[w0] + mv.y*sd.s_rk[w0+1] + mv.z*sd.s_rk[w0+2] + mv.w*sd.s_rk[w0+3];
          d1 += mv.x*sd.s_rk[64+w0] + mv.y*sd.s_rk[64+w0+1] + mv.z*sd.s_rk[64+w0+2] + mv.w*sd.s_rk[64+w0+3];
          d2 += mv.x*sd.s_rk[128+w0] + mv.y*sd.s_rk[128+w0+1] + mv.z*sd.s_rk[128+w0+2] + mv.w*sd.s_rk[128+w0+3];
          d3 += mv.x*sd.s_rk[192+w0] + mv.y*sd.s_rk[192+w0+1] + mv.z*sd.s_rk[192+w0+2] + mv.w*sd.s_rk[192+w0+3];
        }
        float inv = 1.f/(sqrtf(nrm2)+EPSV);
        pr[0] = d0*inv*sd.s_rstr[0];
        pr[1] = d1*inv*sd.s_rstr[1];
        pr[2] = d2*inv*sd.s_rstr[2];
        pr[3] = d3*inv*sd.s_rstr[3];
      }
      #pragma unroll
      for (int r=0;r<4;r++){
        float mx = block_max256(pr[r], sd.s_red);
        float e = expf(pr[r] - mx);
        float sm = block_sum256(e, sd.s_red);
        pr[r] = e/sm;
      }
      __syncthreads();

      // ---- Stage 10: fw/bw assembly + wr update ----
      {
        float wwn = sd.s_wwnew[tid], pn = sd.s_prec[tid];
        #pragma unroll
        for (int r=0;r<4;r++){
          float wro = sd.s_wr[r*256+tid];
          float fw  = (1.f-wwn)*aA[r] - aB[r] + wwn*(sd.s_PQ[r] - pn*wro);
          float bwv = (1.f-wwn)*sd.s_C[r*256+tid] - sd.s_D[r*256+tid] + pn*(sd.s_PQ[4+r] - wwn*wro);
          float wrn = sd.s_modes[r*3+0]*bwv + sd.s_modes[r*3+1]*pr[r] + sd.s_modes[r*3+2]*fw;
          wrS[(size_t)b*1024 + r*256 + tid] = wrn;
          sd.s_wr[r*256+tid] = wrn;
        }
      }
      __syncthreads();

      // ---- Stage 11: rvecT slot = (wr_new @ mem)^T ----
      {
        int r = tid >> 6, w = tid & 63;
        const float* Mb = memS + (size_t)b*16384;
        float acc = 0.f;
        for (int n=0; n<256; n++) acc += sd.s_wr[r*256+n]*Mb[(size_t)n*64 + w];
        cstore(&rvS[(size_t)(slot0+t)*16384 + (r*64 + w)*64 + b], acc);
      }
    }
    epoch++; gbar(subs, root, gen, epoch);
  }

  // ======== final O(T-1) ========
  {
    float accO = bo;
    const float* rvP = rvS + (size_t)(slot0+T-1)*16384;
    const float* hP  = htS + (size_t)(slot0+T-1)*32768;
    float4 pf[4];
    { const float4* s = (const float4*)rvP;
      #pragma unroll
      for (int i=0;i<4;i++) pf[i] = s[tid + i*256]; }
    for (int c = 0; c < 12; c++){
      __syncthreads();
      { float4* d = (float4*)sh.u.glo.A;
        #pragma unroll
        for (int i=0;i<4;i++) d[tid + i*256] = pf[i]; }
      if (c < 11){
        const float4* s = (const float4*)((c < 3) ? (rvP + (c+1)*4096) : (hP + (c-3)*4096));
        #pragma unroll
        for (int i=0;i<4;i++) pf[i] = s[tid + i*256];
      }
      __syncthreads();
      if (c < 4){
        #pragma unroll 8
        for (int kk=0;kk<64;kk++)
          accO += sh.u.glo.A[kk*64 + b_] * sh.Wo[(512 + c*64 + kk)*4 + q_];
      } else {
        int r0 = (c-4)*64;
        #pragma unroll 8
        for (int kk=0;kk<64;kk++)
          accO += clipf_(sh.u.glo.A[kk*64 + b_]) * sh.Wo[(r0 + kk)*4 + q_];
      }
    }
    float v = clipf_(accO);
    if (outmode == 0){
      qacc += v;
      outbuf[(size_t)b_*1024 + (bid*4 + q_)] = qacc;
    } else {
      outbuf[(size_t)b_*1280 + (bid*4 + q_)] = tanhf(v);
    }
  }
}

// ======================================================================================
extern "C" void kernel_launch(void* const* d_in, const int* in_sizes, int n_in,
                              void* d_out, int out_size, void* d_ws, size_t ws_size,
                              hipStream_t stream) {
  const float* img_feat = (const float*)d_in[0];
  const int*   qst      = (const int*)  d_in[1];
  const float* emb      = (const float*)d_in[2];
  const float* img_W    = (const float*)d_in[3];
  const float* img_b    = (const float*)d_in[4];
  const float* q_Wih    = (const float*)d_in[5];
  const float* q_Whh    = (const float*)d_in[6];
  const float* q_b      = (const float*)d_in[7];
  const float* q_Wif    = (const float*)d_in[8];
  const float* q_bif    = (const float*)d_in[9];
  const float* q_Wout   = (const float*)d_in[10];
  const float* q_bout   = (const float*)d_in[11];
  const float* c_Wih    = (const float*)d_in[12];
  const float* c_Whh    = (const float*)d_in[13];
  const float* c_b      = (const float*)d_in[14];
  const float* c_Wif    = (const float*)d_in[15];
  const float* c_bif    = (const float*)d_in[16];
  const float* c_Wout   = (const float*)d_in[17];
  const float* c_bout   = (const float*)d_in[18];
  const float* fc1_W    = (const float*)d_in[19];
  const float* fc1_b    = (const float*)d_in[20];
  const float* fc2_W    = (const float*)d_in[21];
  const float* fc2_b    = (const float*)d_in[22];

  float* ws = (float*)d_ws;
  float* qv    = ws + WS_QV;
  float* gxp   = ws + WS_GXP;
  float* zoneC = ws + WS_ZONEC;
  float* imgf  = ws + WS_IMGF;
  float* combB = ws + WS_COMB;
  float* lastB = ws + WS_LASTB;
  float* hid1  = ws + WS_HID1;
  float* qsum  = ws + WS_QSUM;
  int*   bar   = (int*)(ws + WS_BAR);

  // zero state zone (mem/link/prec/wr/ww/usage/bar)
  hipMemsetAsync(ws, 0, (size_t)WS_ZONEA*4, stream);

  // qv[(t*64+b)][300] = tanh(emb[qst])
  embed_kernel<<<1500, 256, 0, stream>>>(qst, emb, qv);

  // image fc: imgf = img_feat @ img_W + img_b  (split-K 16)
  gemm64<<<dim3(16,16,1), 256, 0, stream>>>(64, 1024, 4096, 16,
      img_feat, 4096, img_W, nullptr, nullptr, zoneC, 0);
  reduce64<<<64, 256, 0, stream>>>(zoneC, 16, 16384, 1024, img_b, imgf, 0);

  // gxp = qv @ q_Wih[0:300]
  gemm64<<<dim3(32,1,20), 256, 0, stream>>>(1280, 2048, 300, 1,
      qv, 300, q_Wih, nullptr, gxp, nullptr, 1);

  // question DNC, 20 steps (persistent), slots 0..19
  dnc_recur<<<256, 256, 0, stream>>>(20, 0, 0,
      gxp, q_Wih + (size_t)300*2048, q_Whh, q_b,
      q_Wif, q_bif, q_Wout, q_bout, ws, qsum, bar);

  // comb = tanh(l2norm(imgf) * qsum/20)
  comb_kernel<<<64, 256, 0, stream>>>(imgf, qsum, combB);

  // reset state zone for controller
  hipMemsetAsync(ws, 0, (size_t)WS_ZONEA*4, stream);

  // cxp = comb @ c_Wih[0:1024]  (split-K 4)
  gemm64<<<dim3(32,4,1), 256, 0, stream>>>(64, 2048, 1024, 4,
      combB, 1024, c_Wih, nullptr, nullptr, zoneC, 0);
  reduce64<<<128, 256, 0, stream>>>(zoneC, 4, 32768, 2048, nullptr, gxp, 0);

  // controller DNC, 1 step (persistent), slot 20 -> lastB[:, :1024]
  dnc_recur<<<256, 256, 0, stream>>>(1, 1, 20,
      gxp, c_Wih + (size_t)1024*2048, c_Whh, c_b,
      c_Wif, c_bif, c_Wout, c_bout, ws, lastB, bar);

  // lastB[:, 1024:1280] = tanh(rvec_ctrl)  (rvec slot 20)
  tanhrvec_kernel<<<64, 256, 0, stream>>>(ws + WS_RVS + (size_t)20*16384, lastB);

  // fc1: hid1 = tanh(lastB @ fc1_W + fc1_b)  (split-K 5)
  gemm64<<<dim3(47,5,1), 256, 0, stream>>>(64, 3000, 1280, 5,
      lastB, 1280, fc1_W, nullptr, nullptr, zoneC, 0);
  reduce64<<<188, 256, 0, stream>>>(zoneC, 5, 48000, 3000, fc1_b, hid1, 1);

  // fc2: logits = hid1 @ fc2_W + fc2_b  (split-K 6)
  gemm64<<<dim3(47,6,1), 256, 0, stream>>>(64, 3000, 3000, 6,
      hid1, 3000, fc2_W, nullptr, nullptr, zoneC, 0);
  reduce64<<<188, 256, 0, stream>>>(zoneC, 6, 48000, 3000, fc2_b, (float*)d_out, 0);
}